// Round 2
// baseline (3038.635 us; speedup 1.0000x reference)
//
#include <hip/hip_runtime.h>
#include <cstdint>
#include <cstddef>

#define NB 128
#define NC 16
#define NT 2048
#define NH 256
#define NG 1024
#define NO 10

typedef _Float16 f16;
typedef _Float16 h2 __attribute__((ext_vector_type(2)));
typedef _Float16 h8 __attribute__((ext_vector_type(8)));
typedef int i32x4 __attribute__((ext_vector_type(4)));

static __device__ __forceinline__ float fdot2(h2 a, h2 b, float c) {
#if __has_builtin(__builtin_amdgcn_fdot2)
  return __builtin_amdgcn_fdot2(a, b, c, false);
#else
  return c + (float)a[0] * (float)b[0] + (float)a[1] * (float)b[1];
#endif
}

// VALU lane swap 2k<->2k+1 via DPP quad_perm [1,0,3,2] (no DS traffic).
static __device__ __forceinline__ float pairswap(float v) {
  int r = __builtin_amdgcn_update_dpp(0, __builtin_bit_cast(int, v),
                                      0xB1, 0xF, 0xF, true);
  return __builtin_bit_cast(float, r);
}

static __device__ __forceinline__ float sigm(float x) {
  return __builtin_amdgcn_rcpf(1.f + __expf(-x));
}
static __device__ __forceinline__ float tanh_(float x) {
  return 1.f - 2.f * __builtin_amdgcn_rcpf(1.f + __expf(2.f * x));
}

// Quantize w_hh (1024x256 f32 row-major) to i8 with per-row scale.
__global__ void prepack_whh_i8(const float* __restrict__ whh,
                               int8_t* __restrict__ wq,
                               float* __restrict__ scale) {
  int row = blockIdx.x;   // 0..1023
  int k   = threadIdx.x;  // 0..255
  float v = whh[row * NH + k];
  float m = fabsf(v);
  for (int off = 32; off; off >>= 1) m = fmaxf(m, __shfl_xor(m, off, 64));
  __shared__ float smax[4];
  if ((k & 63) == 0) smax[k >> 6] = m;
  __syncthreads();
  float mm = fmaxf(fmaxf(smax[0], smax[1]), fmaxf(smax[2], smax[3]));
  float s = fmaxf(mm, 1e-20f) / 127.f;
  int qv = (int)rintf(v / s);
  qv = min(127, max(-127, qv));
  wq[row * NH + k] = (int8_t)qv;
  if (k == 0) scale[row] = s;
}

// One workgroup per batch, 512 threads (8 waves -> 2 waves/SIMD).
//
// Phase A (all 8 waves): recurrent matvec gates = h @ W_hh^T on the MFMA
//   pipe. v_mfma_i32_16x16x32_i8, gates on the N dim (wave w owns gates
//   [w*128, w*128+128) as 8 tiles of 16), K=256 as 8 k-tiles of 32.
//   A operand is BROADCAST h: every lane holds h[kt*32 + (lane>>4)*8 .. +8]
//   (row = lane&15 is don't-care -> all 16 D rows equal). B fragments are
//   prequantized i8 rows gathered once into 64 longs (128 VGPRs).
//   NOTE: A and B use the SAME k-indexing formula, so any consistent
//   bijective k-permutation in the HW layout cancels in the dot product;
//   the only layout dependence is D's col=lane&15 (HW-measured, m89).
//   After the kt chain, acc[0] of lane c holds the exact i32 dot for gate
//   g0+c; lanes 0..15 write it to gbuf (LDS, i32[1024]).
// Phase B (verbatim from the proven kernel): thread t=2u+half does the
//   x-projection halves via fdot2, adds the dequantized gate term once
//   (half 0; half 1 uses scale 0), DPP pair-reduce, sigmoid/tanh, cell
//   update, quantized h byte -> hq[1-p] (linear i8[256], broadcast reads).
__global__ __launch_bounds__(512, 2)
void lstm_main(const float* __restrict__ x,
               const float* __restrict__ w_ih,
               const float* __restrict__ b_ih,
               const float* __restrict__ b_hh,
               const float* __restrict__ w_out,
               const float* __restrict__ b_out,
               const int8_t* __restrict__ wq,
               const float* __restrict__ scales,
               float* __restrict__ out) {
  const int t = threadIdx.x;   // 0..511
  const int l = t & 63;        // lane in wave
  const int w = t >> 6;        // wave 0..7
  const int u = t >> 1;        // hidden unit 0..255
  const int half = t & 1;      // x-proj channel half
  const int b = blockIdx.x;

  __shared__ __align__(16) int8_t hq[2][NH];   // h state, 2 phases, linear
  __shared__ int gbuf[NG];                     // i32 gate pre-activations
  __shared__ __align__(16) f16 xs[64][NC];     // 2 KB staged x
  __shared__ float hT[NH];
  __shared__ float lg[NO];

  // ---------------- one-time loads ----------------
  // MFMA B fragments: lane l holds W[g0 + (l&15)][kt*32 + (l>>4)*8 .. +8]
  long bw[8][8];  // [nt][kt], 128 VGPRs
  {
    const int row16 = l & 15;
    const int koff = (l >> 4) * 8;
#pragma unroll
    for (int nt = 0; nt < 8; ++nt) {
      const int g0 = (w * 8 + nt) * 16;
      const int8_t* rp = wq + (size_t)(g0 + row16) * NH + koff;
#pragma unroll
      for (int kt = 0; kt < 8; ++kt)
        bw[nt][kt] = *(const long*)(rp + kt * 32);
    }
  }
  h2 wih[4][4];  // w_ih half-rows (8 ch) x 4 gates
#pragma unroll
  for (int g4 = 0; g4 < 4; ++g4) {
    int row = u + 256 * g4;
#pragma unroll
    for (int uu = 0; uu < 4; ++uu) {
      h2 t2 = {(f16)w_ih[row * NC + 8 * half + 2 * uu],
               (f16)w_ih[row * NC + 8 * half + 2 * uu + 1]};
      wih[g4][uu] = t2;
    }
  }
  const float K = 1.f / 127.f;
  // gate term is the FULL i32 dot now -> count it exactly once (half 0)
  float sci = half ? 0.f : scales[u] * K;
  float scf = half ? 0.f : scales[256 + u] * K;
  float scg = half ? 0.f : scales[512 + u] * K;
  float sco = half ? 0.f : scales[768 + u] * K;
  // biases only in half 0 (added exactly once per gate sum)
  float bi_ = half ? 0.f : b_ih[u] + b_hh[u];
  float bf_ = half ? 0.f : b_ih[256 + u] + b_hh[256 + u];
  float bg_ = half ? 0.f : b_ih[512 + u] + b_hh[512 + u];
  float bo_ = half ? 0.f : b_ih[768 + u] + b_hh[768 + u];

  // zero h phase buffers (512 B), stage x chunk 0
  ((int8_t*)hq)[t] = 0;
#pragma unroll
  for (int r = 0; r < 2; ++r) {
    int e = t + 512 * r;  // 0..1023 over (c, tt)
    int cc = e >> 6, tt = e & 63;
    xs[tt][cc] = (f16)x[(size_t)(b * NC + cc) * NT + tt];
  }
  __syncthreads();

  // ---------------- recurrence ----------------
  float c_ = 0.f, h_last = 0.f;
  const int agrp = (l >> 4) * 8;  // A-fragment k-subwindow for this lane

#pragma unroll 1
  for (int s = 0; s < NT; ++s) {
    const int p = s & 1;

    // ---- phase A: gates(i32) = h . W_hh rows, on the matrix pipe ----
    long a_[8];
    {
      const int8_t* hp = hq[p] + agrp;
#pragma unroll
      for (int kt = 0; kt < 8; ++kt)
        a_[kt] = *(const long*)(hp + kt * 32);  // broadcast, bank-disjoint
    }
#pragma unroll
    for (int nt = 0; nt < 8; ++nt) {
      i32x4 acc = {0, 0, 0, 0};
#pragma unroll
      for (int kt = 0; kt < 8; ++kt)
        acc = __builtin_amdgcn_mfma_i32_16x16x32_i8(a_[kt], bw[nt][kt], acc,
                                                    0, 0, 0);
      // all D rows identical (broadcast A); lane c has gate g0+c in acc[0]
      if (l < 16) gbuf[(w * 8 + nt) * 16 + l] = acc[0];
    }
    __syncthreads();

    // ---- phase B: x-proj + dequant + nonlinearity (proven path) ----
    float fi = bi_, ff = bf_, fg_ = bg_, fo = bo_;
    {
      h8 xv = *(const h8*)&xs[s & 63][8 * half];
#pragma unroll
      for (int uu = 0; uu < 4; ++uu) {
        h2 xp = {xv[2 * uu], xv[2 * uu + 1]};
        fi = fdot2(xp, wih[0][uu], fi);
        ff = fdot2(xp, wih[1][uu], ff);
        fg_ = fdot2(xp, wih[2][uu], fg_);
        fo = fdot2(xp, wih[3][uu], fo);
      }
    }
    float vi = fi + (float)gbuf[u] * sci;
    float vf = ff + (float)gbuf[256 + u] * scf;
    float vg = fg_ + (float)gbuf[512 + u] * scg;
    float vo = fo + (float)gbuf[768 + u] * sco;
    // pair-reduce (lanes 2u,2u+1) via DPP; bit-identical on both lanes.
    vi += pairswap(vi); vf += pairswap(vf); vg += pairswap(vg); vo += pairswap(vo);

    float ig = sigm(vi);
    float fgate = sigm(vf);
    float gv = tanh_(vg);
    float og = sigm(vo);
    c_ = fgate * c_ + ig * gv;
    float hh = og * tanh_(c_);
    h_last = hh;
    // quantize h (|hh| < 1); one writer per unit, linear layout
    if (!half) hq[1 - p][u] = (int8_t)(int)rintf(hh * 127.f);

    // restage x every 64 steps (extra barrier protects WAR on xs)
    if ((s & 63) == 63 && s != NT - 1) {
      __syncthreads();
#pragma unroll
      for (int r = 0; r < 2; ++r) {
        int e = t + 512 * r;
        int cc = e >> 6, tt = e & 63;
        xs[tt][cc] = (f16)x[(size_t)(b * NC + cc) * NT + (s + 1) + tt];
      }
    }
    __syncthreads();
  }

  // ---------------- head: logits + log_softmax ----------------
  if (!half) hT[u] = h_last;
  __syncthreads();
  if (t < NO) {
    float acc = b_out[t];
    for (int k = 0; k < NH; ++k) acc += hT[k] * w_out[t * NH + k];
    lg[t] = acc;
  }
  __syncthreads();
  if (t == 0) {
    float m = lg[0];
    for (int o = 1; o < NO; ++o) m = fmaxf(m, lg[o]);
    float ssum = 0.f;
    for (int o = 0; o < NO; ++o) ssum += __expf(lg[o] - m);
    float lse = m + __logf(ssum);
    for (int o = 0; o < NO; ++o) out[b * NO + o] = lg[o] - lse;
  }
}

extern "C" void kernel_launch(void* const* d_in, const int* in_sizes, int n_in,
                              void* d_out, int out_size, void* d_ws, size_t ws_size,
                              hipStream_t stream) {
  const float* x    = (const float*)d_in[0];
  const float* wih  = (const float*)d_in[1];
  const float* whh  = (const float*)d_in[2];
  const float* bih  = (const float*)d_in[3];
  const float* bhh  = (const float*)d_in[4];
  const float* wout = (const float*)d_in[5];
  const float* bout = (const float*)d_in[6];
  float* out = (float*)d_out;
  int8_t* wq = (int8_t*)d_ws;                       // 256 KB i8 w_hh
  float* scales = (float*)((char*)d_ws + NG * NH);  // 4 KB row scales

  hipLaunchKernelGGL(prepack_whh_i8, dim3(NG), dim3(NH), 0, stream, whh, wq, scales);
  hipLaunchKernelGGL(lstm_main, dim3(NB), dim3(512), 0, stream,
                     x, wih, bih, bhh, wout, bout, wq, scales, out);
}

// Round 5
// 1862.210 us; speedup vs baseline: 1.6317x; 1.6317x over previous
//
#include <hip/hip_runtime.h>
#include <cstdint>
#include <cstddef>

#define NB 128
#define NC 16
#define NT 2048
#define NH 256
#define NG 1024
#define NO 10

typedef _Float16 f16;
typedef _Float16 h2 __attribute__((ext_vector_type(2)));
typedef _Float16 h8 __attribute__((ext_vector_type(8)));
typedef int i32x4 __attribute__((ext_vector_type(4)));
typedef long long2_ __attribute__((ext_vector_type(2)));

static __device__ __forceinline__ float fdot2(h2 a, h2 b, float c) {
#if __has_builtin(__builtin_amdgcn_fdot2)
  return __builtin_amdgcn_fdot2(a, b, c, false);
#else
  return c + (float)a[0] * (float)b[0] + (float)a[1] * (float)b[1];
#endif
}

// K=64 i8 MFMA (gfx950). Fallback: two chained K=32 on the lo/hi 8-byte
// halves — A and B are sliced identically, so k-coverage is exact.
static __device__ __forceinline__ i32x4 mfma_i8_k64(i32x4 a, i32x4 b, i32x4 c) {
#if __has_builtin(__builtin_amdgcn_mfma_i32_16x16x64_i8)
  return __builtin_amdgcn_mfma_i32_16x16x64_i8(a, b, c, 0, 0, 0);
#else
  long2_ al = __builtin_bit_cast(long2_, a);
  long2_ bl = __builtin_bit_cast(long2_, b);
  c = __builtin_amdgcn_mfma_i32_16x16x32_i8(al[0], bl[0], c, 0, 0, 0);
  c = __builtin_amdgcn_mfma_i32_16x16x32_i8(al[1], bl[1], c, 0, 0, 0);
  return c;
#endif
}

static __device__ __forceinline__ float sigm(float x) {
  return __builtin_amdgcn_rcpf(1.f + __expf(-x));
}
static __device__ __forceinline__ float tanh_(float x) {
  return 1.f - 2.f * __builtin_amdgcn_rcpf(1.f + __expf(2.f * x));
}

// Quantize w_hh (1024x256 f32 row-major) to i8 with per-row scale.
__global__ void prepack_whh_i8(const float* __restrict__ whh,
                               int8_t* __restrict__ wq,
                               float* __restrict__ scale) {
  int row = blockIdx.x;   // 0..1023
  int k   = threadIdx.x;  // 0..255
  float v = whh[row * NH + k];
  float m = fabsf(v);
  for (int off = 32; off; off >>= 1) m = fmaxf(m, __shfl_xor(m, off, 64));
  __shared__ float smax[4];
  if ((k & 63) == 0) smax[k >> 6] = m;
  __syncthreads();
  float mm = fmaxf(fmaxf(smax[0], smax[1]), fmaxf(smax[2], smax[3]));
  float s = fmaxf(mm, 1e-20f) / 127.f;
  int qv = (int)rintf(v / s);
  qv = min(127, max(-127, qv));
  wq[row * NH + k] = (int8_t)qv;
  if (k == 0) scale[row] = s;
}

// One workgroup per batch, 512 threads (8 waves -> 2 waves/SIMD).
//
// Wave w owns hidden units [32w, 32w+32). Its 8 MFMA n-tiles are the 4
// gate types x 2 unit-halves for those units, K=256 as 4 k-tiles of 64
// (v_mfma_i32_16x16x64_i8, 4-VGPR operands -> half the instruction count
// of the x32 shape). A is BROADCAST h (all 16 rows equal), so D rows are
// identical and lane l holds gate (tilebase + (l&15)) in acc[0].
// Consequence: lane l = 16*grp + r, with sel = grp&1, holds ALL FOUR gate
// pre-activations for unit uu = 32w + 16*sel + r in registers -> phase B
// (x-projection fdot2, dequant, nonlinearity, cell update) is fully
// in-register and in-lane: NO gate LDS buffer, NO phase-A/B barrier, no
// DPP pair-reduce. Groups 2,3 duplicate groups 0,1 (bit-identical);
// lanes l<32 are the unique writers of h. One barrier per step.
__global__ __launch_bounds__(512, 2)
void lstm_main(const float* __restrict__ x,
               const float* __restrict__ w_ih,
               const float* __restrict__ b_ih,
               const float* __restrict__ b_hh,
               const float* __restrict__ w_out,
               const float* __restrict__ b_out,
               const int8_t* __restrict__ wq,
               const float* __restrict__ scales,
               float* __restrict__ out) {
  const int t = threadIdx.x;   // 0..511
  const int l = t & 63;        // lane in wave
  const int w = t >> 6;        // wave 0..7
  const int b = blockIdx.x;
  const int row16 = l & 15;    // MFMA col / unit-within-16
  const int grp = l >> 4;      // lane quarter 0..3 (k-segment of A/B)
  const int sel = grp & 1;     // which unit-half this lane finalizes
  const int uu = 32 * w + 16 * sel + row16;  // unit this lane finalizes

  __shared__ __align__(16) int8_t hq[2][NH];  // h state, 2 phases, linear
  __shared__ __align__(16) f16 xs[64][NC];    // 2 KB staged x
  __shared__ float hT[NH];
  __shared__ float lg[NO];

  // ---------------- one-time loads ----------------
  // B fragments: tile (gt,hf) rows = 256*gt + 32*w + 16*hf + row16,
  // lane k-segment = kt*64 + grp*16 (16 bytes). Same k formula as A ->
  // any consistent HW k-permutation cancels in the dot.
  i32x4 bw[4][2][4];  // [gate][half][kt] = 128 VGPRs (AGPR-eligible)
#pragma unroll
  for (int gt = 0; gt < 4; ++gt)
#pragma unroll
    for (int hf = 0; hf < 2; ++hf) {
      const int8_t* rp =
          wq + (size_t)(256 * gt + 32 * w + 16 * hf + row16) * NH + grp * 16;
#pragma unroll
      for (int kt = 0; kt < 4; ++kt)
        bw[gt][hf][kt] = *(const i32x4*)(rp + kt * 64);
    }

  // w_ih rows for this lane's unit: 4 gates x 16 channels as f16 pairs
  h2 wih[4][8];
#pragma unroll
  for (int gt = 0; gt < 4; ++gt) {
    const float* rp = w_ih + (size_t)(256 * gt + uu) * NC;
#pragma unroll
    for (int q = 0; q < 8; ++q) {
      h2 t2 = {(f16)rp[2 * q], (f16)rp[2 * q + 1]};
      wih[gt][q] = t2;
    }
  }
  const float K = 1.f / 127.f;
  float sc[4], bb[4];
#pragma unroll
  for (int gt = 0; gt < 4; ++gt) {
    sc[gt] = scales[256 * gt + uu] * K;               // dequant scale
    bb[gt] = b_ih[256 * gt + uu] + b_hh[256 * gt + uu];  // fused bias
  }

  // zero h phase buffers (512 B), stage x chunk 0
  ((int8_t*)hq)[t] = 0;
#pragma unroll
  for (int r = 0; r < 2; ++r) {
    int e = t + 512 * r;  // 0..1023 over (c, tt)
    int cc = e >> 6, tt = e & 63;
    xs[tt][cc] = (f16)x[(size_t)(b * NC + cc) * NT + tt];
  }
  __syncthreads();

  // ---------------- recurrence ----------------
  float c_ = 0.f, h_last = 0.f;

#pragma unroll 1
  for (int s = 0; s < NT; ++s) {
    const int p = s & 1;

    // A fragments: lane reads h[kt*64 + grp*16 .. +16) (broadcast within
    // each 16-lane group; groups hit disjoint bank quads -> conflict-free)
    const int8_t* hp = hq[p] + grp * 16;
    i32x4 a_[4];
#pragma unroll
    for (int kt = 0; kt < 4; ++kt) a_[kt] = *(const i32x4*)(hp + kt * 64);

    // x-projection for this lane's unit (VALU; overlaps MFMA issue)
    h8 xlo = *(const h8*)&xs[s & 63][0];
    h8 xhi = *(const h8*)&xs[s & 63][8];
    float xp[4];
#pragma unroll
    for (int gt = 0; gt < 4; ++gt) {
      float acc = bb[gt];
#pragma unroll
      for (int q = 0; q < 4; ++q) {
        h2 xa = {xlo[2 * q], xlo[2 * q + 1]};
        acc = fdot2(xa, wih[gt][q], acc);
      }
#pragma unroll
      for (int q = 0; q < 4; ++q) {
        h2 xa = {xhi[2 * q], xhi[2 * q + 1]};
        acc = fdot2(xa, wih[gt][q + 4], acc);
      }
      xp[gt] = acc;
    }

    // 8 tiles x 4 chained k-steps = 32 MFMAs (matrix pipe)
    i32x4 acc[4][2];
#pragma unroll
    for (int gt = 0; gt < 4; ++gt)
#pragma unroll
      for (int hf = 0; hf < 2; ++hf) {
        i32x4 ac = {0, 0, 0, 0};
#pragma unroll
        for (int kt = 0; kt < 4; ++kt)
          ac = mfma_i8_k64(a_[kt], bw[gt][hf][kt], ac);
        acc[gt][hf] = ac;
      }

    // gates for unit uu, fully in-register (constant indices both arms)
    float gv[4];
#pragma unroll
    for (int gt = 0; gt < 4; ++gt) {
      int d = sel ? acc[gt][1][0] : acc[gt][0][0];
      gv[gt] = xp[gt] + (float)d * sc[gt];
    }

    float ig = sigm(gv[0]);
    float fg = sigm(gv[1]);
    float gg = tanh_(gv[2]);
    float og = sigm(gv[3]);
    c_ = fg * c_ + ig * gg;
    float hh = og * tanh_(c_);
    h_last = hh;
    // quantize h (|hh| < 1); lanes 0..31 are the unique writers
    if (l < 32) hq[1 - p][uu] = (int8_t)(int)rintf(hh * 127.f);

    // restage x every 64 steps (extra barrier protects WAR on xs)
    if ((s & 63) == 63 && s != NT - 1) {
      __syncthreads();
#pragma unroll
      for (int r = 0; r < 2; ++r) {
        int e = t + 512 * r;
        int cc = e >> 6, tt = e & 63;
        xs[tt][cc] = (f16)x[(size_t)(b * NC + cc) * NT + (s + 1) + tt];
      }
    }
    __syncthreads();
  }

  // ---------------- head: logits + log_softmax ----------------
  if (l < 32) hT[uu] = h_last;
  __syncthreads();
  if (t < NO) {
    float acc = b_out[t];
    for (int k = 0; k < NH; ++k) acc += hT[k] * w_out[t * NH + k];
    lg[t] = acc;
  }
  __syncthreads();
  if (t == 0) {
    float m = lg[0];
    for (int o = 1; o < NO; ++o) m = fmaxf(m, lg[o]);
    float ssum = 0.f;
    for (int o = 0; o < NO; ++o) ssum += __expf(lg[o] - m);
    float lse = m + __logf(ssum);
    for (int o = 0; o < NO; ++o) out[b * NO + o] = lg[o] - lse;
  }
}

extern "C" void kernel_launch(void* const* d_in, const int* in_sizes, int n_in,
                              void* d_out, int out_size, void* d_ws, size_t ws_size,
                              hipStream_t stream) {
  const float* x    = (const float*)d_in[0];
  const float* wih  = (const float*)d_in[1];
  const float* whh  = (const float*)d_in[2];
  const float* bih  = (const float*)d_in[3];
  const float* bhh  = (const float*)d_in[4];
  const float* wout = (const float*)d_in[5];
  const float* bout = (const float*)d_in[6];
  float* out = (float*)d_out;
  int8_t* wq = (int8_t*)d_ws;                       // 256 KB i8 w_hh
  float* scales = (float*)((char*)d_ws + NG * NH);  // 4 KB row scales

  hipLaunchKernelGGL(prepack_whh_i8, dim3(NG), dim3(NH), 0, stream, whh, wq, scales);
  hipLaunchKernelGGL(lstm_main, dim3(NB), dim3(512), 0, stream,
                     x, wih, bih, bhh, wout, bout, wq, scales, out);
}